// Round 1
// baseline (106229.492 us; speedup 1.0000x reference)
//
#include <hip/hip_runtime.h>
#include <math.h>

#define NSTEP 4095   // T-1 sequence steps
#define EDIM  512
#define HDIM  1024
#define GDIM  4096   // 4*H
#define KDIM  1024   // 2E == H == 1024 for both GEMMs
#define CDIM  1221
#define NWG   256    // scan workgroups, 4 hidden units each

__device__ __forceinline__ float sigmoidf_(float v) {
    return 1.0f / (1.0f + __expf(-v));
}

// ---------------------------------------------------------------------------
// GEMM1: xg[m][n] = sum_k A[m][k]*W_ih[n][k] + b_ih[n] + b_hh[n]
//   A[m][k] = emb[x[m]][k]        (k < 512)
//           = emb[x[4095]][k-512] (k >= 512)
// 128x128 tile, BK=8, 256 threads, 8x8 micro-tile (2x2 blocks of 4x4).
// ---------------------------------------------------------------------------
__global__ __launch_bounds__(256) void gemm_emb_kernel(
    const int* __restrict__ x, const float* __restrict__ emb,
    const float* __restrict__ W, const float* __restrict__ b_ih,
    const float* __restrict__ b_hh, float* __restrict__ xg)
{
    __shared__ float As[8][128];
    __shared__ float Bs[8][128];
    const int tid = threadIdx.x;
    const int bm = blockIdx.y * 128, bn = blockIdx.x * 128;
    const int tx = tid & 15, ty = tid >> 4;
    const int lrow = tid >> 1;
    const int lk4  = (tid & 1) * 4;
    const int lastTok = x[NSTEP];
    const int am = bm + lrow;
    const int tokRow = (am < NSTEP) ? x[am] : 0;
    const int bnrow = bn + lrow;

    float acc[8][8];
#pragma unroll
    for (int i = 0; i < 8; ++i)
#pragma unroll
        for (int j = 0; j < 8; ++j) acc[i][j] = 0.0f;

    for (int k0 = 0; k0 < KDIM; k0 += 8) {
        const int k = k0 + lk4;
        float4 av = make_float4(0.f, 0.f, 0.f, 0.f);
        if (am < NSTEP) {
            const int tok = (k < EDIM) ? tokRow : lastTok;
            const int kk  = (k < EDIM) ? k : (k - EDIM);
            av = *(const float4*)(emb + (size_t)tok * EDIM + kk);
        }
        const float4 bv = *(const float4*)(W + (size_t)bnrow * KDIM + k);
        __syncthreads();   // previous tile consumed
        As[lk4 + 0][lrow] = av.x; As[lk4 + 1][lrow] = av.y;
        As[lk4 + 2][lrow] = av.z; As[lk4 + 3][lrow] = av.w;
        Bs[lk4 + 0][lrow] = bv.x; Bs[lk4 + 1][lrow] = bv.y;
        Bs[lk4 + 2][lrow] = bv.z; Bs[lk4 + 3][lrow] = bv.w;
        __syncthreads();
#pragma unroll
        for (int kk = 0; kk < 8; ++kk) {
            const float4 a0 = *(const float4*)&As[kk][ty * 4];
            const float4 a1 = *(const float4*)&As[kk][ty * 4 + 64];
            const float4 b0 = *(const float4*)&Bs[kk][tx * 4];
            const float4 b1 = *(const float4*)&Bs[kk][tx * 4 + 64];
            const float a[8] = {a0.x, a0.y, a0.z, a0.w, a1.x, a1.y, a1.z, a1.w};
            const float b[8] = {b0.x, b0.y, b0.z, b0.w, b1.x, b1.y, b1.z, b1.w};
#pragma unroll
            for (int i = 0; i < 8; ++i)
#pragma unroll
                for (int j = 0; j < 8; ++j) acc[i][j] += a[i] * b[j];
        }
    }
#pragma unroll
    for (int i = 0; i < 8; ++i) {
        const int m = bm + ((i < 4) ? (ty * 4 + i) : (64 + ty * 4 + i - 4));
        if (m >= NSTEP) continue;
#pragma unroll
        for (int j = 0; j < 8; ++j) {
            const int n = bn + ((j < 4) ? (tx * 4 + j) : (64 + tx * 4 + j - 4));
            xg[(size_t)m * GDIM + n] = acc[i][j] + b_ih[n] + b_hh[n];
        }
    }
}

// ---------------------------------------------------------------------------
// GEMM2: out[m][n] = sum_k hs[m][k]*W_out[n][k] + b_out[n]   (N=1221)
// ---------------------------------------------------------------------------
__global__ __launch_bounds__(256) void gemm_out_kernel(
    const float* __restrict__ A, const float* __restrict__ W,
    const float* __restrict__ bias, float* __restrict__ C)
{
    __shared__ float As[8][128];
    __shared__ float Bs[8][128];
    const int tid = threadIdx.x;
    const int bm = blockIdx.y * 128, bn = blockIdx.x * 128;
    const int tx = tid & 15, ty = tid >> 4;
    const int lrow = tid >> 1;
    const int lk4  = (tid & 1) * 4;
    const int am = bm + lrow;
    const int bnrow = bn + lrow;

    float acc[8][8];
#pragma unroll
    for (int i = 0; i < 8; ++i)
#pragma unroll
        for (int j = 0; j < 8; ++j) acc[i][j] = 0.0f;

    for (int k0 = 0; k0 < KDIM; k0 += 8) {
        const int k = k0 + lk4;
        float4 av = make_float4(0.f, 0.f, 0.f, 0.f);
        if (am < NSTEP) av = *(const float4*)(A + (size_t)am * KDIM + k);
        float4 bv = make_float4(0.f, 0.f, 0.f, 0.f);
        if (bnrow < CDIM) bv = *(const float4*)(W + (size_t)bnrow * KDIM + k);
        __syncthreads();
        As[lk4 + 0][lrow] = av.x; As[lk4 + 1][lrow] = av.y;
        As[lk4 + 2][lrow] = av.z; As[lk4 + 3][lrow] = av.w;
        Bs[lk4 + 0][lrow] = bv.x; Bs[lk4 + 1][lrow] = bv.y;
        Bs[lk4 + 2][lrow] = bv.z; Bs[lk4 + 3][lrow] = bv.w;
        __syncthreads();
#pragma unroll
        for (int kk = 0; kk < 8; ++kk) {
            const float4 a0 = *(const float4*)&As[kk][ty * 4];
            const float4 a1 = *(const float4*)&As[kk][ty * 4 + 64];
            const float4 b0 = *(const float4*)&Bs[kk][tx * 4];
            const float4 b1 = *(const float4*)&Bs[kk][tx * 4 + 64];
            const float a[8] = {a0.x, a0.y, a0.z, a0.w, a1.x, a1.y, a1.z, a1.w};
            const float b[8] = {b0.x, b0.y, b0.z, b0.w, b1.x, b1.y, b1.z, b1.w};
#pragma unroll
            for (int i = 0; i < 8; ++i)
#pragma unroll
                for (int j = 0; j < 8; ++j) acc[i][j] += a[i] * b[j];
        }
    }
#pragma unroll
    for (int i = 0; i < 8; ++i) {
        const int m = bm + ((i < 4) ? (ty * 4 + i) : (64 + ty * 4 + i - 4));
        if (m >= NSTEP) continue;
#pragma unroll
        for (int j = 0; j < 8; ++j) {
            const int n = bn + ((j < 4) ? (tx * 4 + j) : (64 + tx * 4 + j - 4));
            if (n < CDIM) C[(size_t)m * CDIM + n] = acc[i][j] + bias[n];
        }
    }
}

// ---------------------------------------------------------------------------
// Persistent LSTM scan. 256 WGs x 256 threads, WG g owns hidden units
// g*4..g*4+3 (16 gate rows of W_hh held in registers: 64 VGPRs/thread).
// Cross-WG handoff of h each step via double-buffered h_buf + per-WG flags
// (agent-scope atomics). Flags hold last completed step; 0xAA poison is
// negative so no init pass is needed.
// ---------------------------------------------------------------------------
__global__ __launch_bounds__(256) void scan_kernel(
    const float* __restrict__ xg, const float* __restrict__ Whh,
    float* __restrict__ hs, float* h_buf, int* flags)
{
    __shared__ float h_s[HDIM];
    __shared__ float gate_s[16];
    __shared__ float c_s[4];
    const int g = blockIdx.x, tid = threadIdx.x;
    const int seg = tid & 15, lr = tid >> 4;     // lr = q*4 + j
    const int q = lr >> 2, j = lr & 3;
    const int grow = q * HDIM + g * 4 + j;       // gate row in W_hh

    // weights: thread covers cols i*64 + seg*4 .. +3, i = 0..15
    float4 w4[16];
#pragma unroll
    for (int i = 0; i < 16; ++i)
        w4[i] = *(const float4*)(Whh + (size_t)grow * KDIM + i * 64 + seg * 4);

    for (int i = tid; i < HDIM; i += 256) h_s[i] = 0.0f;
    if (tid < 4) c_s[tid] = 0.0f;
    __syncthreads();

    for (int t = 1; t <= NSTEP; ++t) {
        // issue xg load early; it's independent of the spin below
        float xgv = 0.0f;
        if (seg == 0) xgv = xg[(size_t)(t - 1) * GDIM + grow];

        if (t > 1) {
            const int par = (t - 1) & 1;
            // wait for all producers of h_{t-1}
            while (__hip_atomic_load(&flags[par * NWG + tid], __ATOMIC_ACQUIRE,
                                     __HIP_MEMORY_SCOPE_AGENT) < t - 1) {
                __builtin_amdgcn_s_sleep(1);
            }
            __syncthreads();
#pragma unroll
            for (int k = 0; k < 4; ++k) {
                const int el = tid + k * 256;
                h_s[el] = __hip_atomic_load(&h_buf[par * HDIM + el],
                                            __ATOMIC_RELAXED,
                                            __HIP_MEMORY_SCOPE_AGENT);
            }
            __syncthreads();
        }

        // GEMV: partial dot over this thread's 64 columns
        float acc = 0.0f;
#pragma unroll
        for (int i = 0; i < 16; ++i) {
            const float4 h4 = *(const float4*)&h_s[i * 64 + seg * 4];
            acc += w4[i].x * h4.x + w4[i].y * h4.y +
                   w4[i].z * h4.z + w4[i].w * h4.w;
        }
        acc += __shfl_xor(acc, 1, 64);
        acc += __shfl_xor(acc, 2, 64);
        acc += __shfl_xor(acc, 4, 64);
        acc += __shfl_xor(acc, 8, 64);
        if (seg == 0) gate_s[lr] = acc + xgv;
        __syncthreads();

        if (tid < 4) {
            const int jj = tid;
            const float ig = sigmoidf_(gate_s[jj]);
            const float fg = sigmoidf_(gate_s[4 + jj]);
            const float gg = tanhf(gate_s[8 + jj]);
            const float og = sigmoidf_(gate_s[12 + jj]);
            const float c  = fg * c_s[jj] + ig * gg;
            c_s[jj] = c;
            const float h = og * tanhf(c);
            hs[(size_t)(t - 1) * HDIM + g * 4 + jj] = h;
            __hip_atomic_store(&h_buf[(t & 1) * HDIM + g * 4 + jj], h,
                               __ATOMIC_RELEASE, __HIP_MEMORY_SCOPE_AGENT);
        }
        __syncthreads();   // all stores drained (vmcnt) before flag
        if (tid == 0)
            __hip_atomic_store(&flags[(t & 1) * NWG + g], t,
                               __ATOMIC_RELEASE, __HIP_MEMORY_SCOPE_AGENT);
    }
}

extern "C" void kernel_launch(void* const* d_in, const int* in_sizes, int n_in,
                              void* d_out, int out_size, void* d_ws, size_t ws_size,
                              hipStream_t stream)
{
    const int*   x     = (const int*)d_in[0];
    const float* emb   = (const float*)d_in[1];
    const float* W_ih  = (const float*)d_in[2];
    const float* W_hh  = (const float*)d_in[3];
    const float* b_ih  = (const float*)d_in[4];
    const float* b_hh  = (const float*)d_in[5];
    const float* W_out = (const float*)d_in[6];
    const float* b_out = (const float*)d_in[7];
    float* out = (float*)d_out;

    float* xg    = (float*)d_ws;                       // 4095*4096 f32
    float* hs    = xg + (size_t)NSTEP * GDIM;          // 4095*1024 f32
    float* h_buf = hs + (size_t)NSTEP * HDIM;          // 2*1024 f32
    int*   flags = (int*)(h_buf + 2 * HDIM);           // 2*256 int

    dim3 blk(256);
    dim3 g1(GDIM / 128, 32);                           // 32 x 32
    gemm_emb_kernel<<<g1, blk, 0, stream>>>(x, emb, W_ih, b_ih, b_hh, xg);

    scan_kernel<<<dim3(NWG), blk, 0, stream>>>(xg, W_hh, hs, h_buf, flags);

    dim3 g2((CDIM + 127) / 128, 32);                   // 10 x 32
    gemm_out_kernel<<<g2, blk, 0, stream>>>(hs, W_out, b_out, out);
}

// Round 2
// 54764.124 us; speedup vs baseline: 1.9398x; 1.9398x over previous
//
#include <hip/hip_runtime.h>
#include <math.h>

#define NSTEP 4095   // T-1 sequence steps
#define EDIM  512
#define HDIM  1024
#define GDIM  4096   // 4*H
#define KDIM  1024   // 2E == H == 1024 for both GEMMs
#define CDIM  1221
#define NWG   256    // scan workgroups, 4 hidden units each

__device__ __forceinline__ float sigmoidf_(float v) {
    return 1.0f / (1.0f + __expf(-v));
}
__device__ __forceinline__ float tanhf_(float v) {
    v = fminf(fmaxf(v, -15.0f), 15.0f);      // avoid inf/inf NaN
    const float e2 = __expf(2.0f * v);
    return (e2 - 1.0f) / (e2 + 1.0f);
}

// ---------------------------------------------------------------------------
// GEMM1: xg[m][n] = sum_k A[m][k]*W_ih[n][k] + b_ih[n] + b_hh[n]
//   A[m][k] = emb[x[m]][k] (k<512) ; emb[x[4095]][k-512] (k>=512)
// ---------------------------------------------------------------------------
__global__ __launch_bounds__(256) void gemm_emb_kernel(
    const int* __restrict__ x, const float* __restrict__ emb,
    const float* __restrict__ W, const float* __restrict__ b_ih,
    const float* __restrict__ b_hh, float* __restrict__ xg)
{
    __shared__ float As[8][128];
    __shared__ float Bs[8][128];
    const int tid = threadIdx.x;
    const int bm = blockIdx.y * 128, bn = blockIdx.x * 128;
    const int tx = tid & 15, ty = tid >> 4;
    const int lrow = tid >> 1;
    const int lk4  = (tid & 1) * 4;
    const int lastTok = x[NSTEP];
    const int am = bm + lrow;
    const int tokRow = (am < NSTEP) ? x[am] : 0;
    const int bnrow = bn + lrow;

    float acc[8][8];
#pragma unroll
    for (int i = 0; i < 8; ++i)
#pragma unroll
        for (int j = 0; j < 8; ++j) acc[i][j] = 0.0f;

    for (int k0 = 0; k0 < KDIM; k0 += 8) {
        const int k = k0 + lk4;
        float4 av = make_float4(0.f, 0.f, 0.f, 0.f);
        if (am < NSTEP) {
            const int tok = (k < EDIM) ? tokRow : lastTok;
            const int kk  = (k < EDIM) ? k : (k - EDIM);
            av = *(const float4*)(emb + (size_t)tok * EDIM + kk);
        }
        const float4 bv = *(const float4*)(W + (size_t)bnrow * KDIM + k);
        __syncthreads();
        As[lk4 + 0][lrow] = av.x; As[lk4 + 1][lrow] = av.y;
        As[lk4 + 2][lrow] = av.z; As[lk4 + 3][lrow] = av.w;
        Bs[lk4 + 0][lrow] = bv.x; Bs[lk4 + 1][lrow] = bv.y;
        Bs[lk4 + 2][lrow] = bv.z; Bs[lk4 + 3][lrow] = bv.w;
        __syncthreads();
#pragma unroll
        for (int kk = 0; kk < 8; ++kk) {
            const float4 a0 = *(const float4*)&As[kk][ty * 4];
            const float4 a1 = *(const float4*)&As[kk][ty * 4 + 64];
            const float4 b0 = *(const float4*)&Bs[kk][tx * 4];
            const float4 b1 = *(const float4*)&Bs[kk][tx * 4 + 64];
            const float a[8] = {a0.x, a0.y, a0.z, a0.w, a1.x, a1.y, a1.z, a1.w};
            const float b[8] = {b0.x, b0.y, b0.z, b0.w, b1.x, b1.y, b1.z, b1.w};
#pragma unroll
            for (int i = 0; i < 8; ++i)
#pragma unroll
                for (int j = 0; j < 8; ++j) acc[i][j] += a[i] * b[j];
        }
    }
#pragma unroll
    for (int i = 0; i < 8; ++i) {
        const int m = bm + ((i < 4) ? (ty * 4 + i) : (64 + ty * 4 + i - 4));
        if (m >= NSTEP) continue;
#pragma unroll
        for (int j = 0; j < 8; ++j) {
            const int n = bn + ((j < 4) ? (tx * 4 + j) : (64 + tx * 4 + j - 4));
            xg[(size_t)m * GDIM + n] = acc[i][j] + b_ih[n] + b_hh[n];
        }
    }
}

// ---------------------------------------------------------------------------
// GEMM2: out[m][n] = sum_k hs[m][k]*W_out[n][k] + b_out[n]   (N=1221)
// ---------------------------------------------------------------------------
__global__ __launch_bounds__(256) void gemm_out_kernel(
    const float* __restrict__ A, const float* __restrict__ W,
    const float* __restrict__ bias, float* __restrict__ C)
{
    __shared__ float As[8][128];
    __shared__ float Bs[8][128];
    const int tid = threadIdx.x;
    const int bm = blockIdx.y * 128, bn = blockIdx.x * 128;
    const int tx = tid & 15, ty = tid >> 4;
    const int lrow = tid >> 1;
    const int lk4  = (tid & 1) * 4;
    const int am = bm + lrow;
    const int bnrow = bn + lrow;

    float acc[8][8];
#pragma unroll
    for (int i = 0; i < 8; ++i)
#pragma unroll
        for (int j = 0; j < 8; ++j) acc[i][j] = 0.0f;

    for (int k0 = 0; k0 < KDIM; k0 += 8) {
        const int k = k0 + lk4;
        float4 av = make_float4(0.f, 0.f, 0.f, 0.f);
        if (am < NSTEP) av = *(const float4*)(A + (size_t)am * KDIM + k);
        float4 bv = make_float4(0.f, 0.f, 0.f, 0.f);
        if (bnrow < CDIM) bv = *(const float4*)(W + (size_t)bnrow * KDIM + k);
        __syncthreads();
        As[lk4 + 0][lrow] = av.x; As[lk4 + 1][lrow] = av.y;
        As[lk4 + 2][lrow] = av.z; As[lk4 + 3][lrow] = av.w;
        Bs[lk4 + 0][lrow] = bv.x; Bs[lk4 + 1][lrow] = bv.y;
        Bs[lk4 + 2][lrow] = bv.z; Bs[lk4 + 3][lrow] = bv.w;
        __syncthreads();
#pragma unroll
        for (int kk = 0; kk < 8; ++kk) {
            const float4 a0 = *(const float4*)&As[kk][ty * 4];
            const float4 a1 = *(const float4*)&As[kk][ty * 4 + 64];
            const float4 b0 = *(const float4*)&Bs[kk][tx * 4];
            const float4 b1 = *(const float4*)&Bs[kk][tx * 4 + 64];
            const float a[8] = {a0.x, a0.y, a0.z, a0.w, a1.x, a1.y, a1.z, a1.w};
            const float b[8] = {b0.x, b0.y, b0.z, b0.w, b1.x, b1.y, b1.z, b1.w};
#pragma unroll
            for (int i = 0; i < 8; ++i)
#pragma unroll
                for (int j = 0; j < 8; ++j) acc[i][j] += a[i] * b[j];
        }
    }
#pragma unroll
    for (int i = 0; i < 8; ++i) {
        const int m = bm + ((i < 4) ? (ty * 4 + i) : (64 + ty * 4 + i - 4));
        if (m >= NSTEP) continue;
#pragma unroll
        for (int j = 0; j < 8; ++j) {
            const int n = bn + ((j < 4) ? (tx * 4 + j) : (64 + tx * 4 + j - 4));
            if (n < CDIM) C[(size_t)m * CDIM + n] = acc[i][j] + bias[n];
        }
    }
}

// ---------------------------------------------------------------------------
// Persistent LSTM scan. 256 WGs x 256 threads; WG g owns hidden units
// g*4..g*4+3 (16 gate rows of W_hh pinned in 64 VGPRs/thread via asm).
// Handoff: per-WG flags, RELAXED polling (wave-min reduce over 64 flags per
// wave), one acquire fence per step. Wave w reads exactly the h-slice whose
// flags it verified, so no barrier between poll and h_buf read.
// ---------------------------------------------------------------------------
__global__ __launch_bounds__(256, 1) void scan_kernel(
    const float* __restrict__ xg, const float* __restrict__ Whh,
    float* __restrict__ hs, float* h_buf, int* flags)
{
    __shared__ float h_s[HDIM];
    __shared__ float gate_s[16];
    __shared__ float c_s[4];
    const int g = blockIdx.x, tid = threadIdx.x;
    const int lane = tid & 63, wv = tid >> 6;
    const int seg = tid & 15, lr = tid >> 4;     // lr = q*4 + j
    const int q = lr >> 2, j = lr & 3;
    const int grow = q * HDIM + g * 4 + j;       // gate row in W_hh

    // weights: thread covers cols i*64 + seg*4 .. +3, i = 0..15
    float4 w4[16];
#pragma unroll
    for (int i = 0; i < 16; ++i)
        w4[i] = *(const float4*)(Whh + (size_t)grow * KDIM + i * 64 + seg * 4);
    // Pin in VGPRs: empty asm is now the def; compiler can't re-load per step.
#pragma unroll
    for (int i = 0; i < 16; ++i)
        asm volatile("" : "+v"(w4[i].x), "+v"(w4[i].y), "+v"(w4[i].z), "+v"(w4[i].w));

    for (int i = tid; i < HDIM; i += 256) h_s[i] = 0.0f;
    if (tid < 4) c_s[tid] = 0.0f;
    __syncthreads();

    for (int t = 1; t <= NSTEP; ++t) {
        // xg load is independent of the handshake; issue early
        float xgv = 0.0f;
        if (seg == 0) xgv = xg[(size_t)(t - 1) * GDIM + grow];

        if (t > 1) {
            const int par = (t - 1) & 1;
            const int* fl = flags + par * NWG;
            int spins = 0;
            for (;;) {
                int f = __hip_atomic_load(&fl[tid], __ATOMIC_RELAXED,
                                          __HIP_MEMORY_SCOPE_AGENT);
#pragma unroll
                for (int d = 1; d < 64; d <<= 1) f = min(f, __shfl_xor(f, d, 64));
                if (f >= t - 1) break;
                __builtin_amdgcn_s_sleep(1);
                if ((++spins & 31) == 31)   // livelock insurance: force refetch
                    __builtin_amdgcn_fence(__ATOMIC_ACQUIRE, "agent");
            }
            __builtin_amdgcn_fence(__ATOMIC_ACQUIRE, "agent");
            const int base = wv * 256 + lane;   // slice this wave verified
#pragma unroll
            for (int k = 0; k < 4; ++k) {
                const int el = base + k * 64;
                h_s[el] = __hip_atomic_load(&h_buf[par * HDIM + el],
                                            __ATOMIC_RELAXED,
                                            __HIP_MEMORY_SCOPE_AGENT);
            }
        }
        __syncthreads();   // (B) h_s ready

        // GEMV: partial dot over this thread's 64 columns
        float acc = 0.0f;
#pragma unroll
        for (int i = 0; i < 16; ++i) {
            const float4 h4 = *(const float4*)&h_s[i * 64 + seg * 4];
            acc += w4[i].x * h4.x + w4[i].y * h4.y +
                   w4[i].z * h4.z + w4[i].w * h4.w;
        }
        acc += __shfl_xor(acc, 1, 64);
        acc += __shfl_xor(acc, 2, 64);
        acc += __shfl_xor(acc, 4, 64);
        acc += __shfl_xor(acc, 8, 64);
        if (seg == 0) gate_s[lr] = acc + xgv;
        __syncthreads();   // (C) gate_s ready; also: all h_buf reads complete

        if (tid < 4) {
            const int jj = tid;
            const float ig = sigmoidf_(gate_s[jj]);
            const float fg = sigmoidf_(gate_s[4 + jj]);
            const float gg = tanhf_(gate_s[8 + jj]);
            const float og = sigmoidf_(gate_s[12 + jj]);
            const float c  = fg * c_s[jj] + ig * gg;
            c_s[jj] = c;
            const float h = og * tanhf_(c);
            hs[(size_t)(t - 1) * HDIM + g * 4 + jj] = h;
            __hip_atomic_store(&h_buf[(t & 1) * HDIM + g * 4 + jj], h,
                               __ATOMIC_RELAXED, __HIP_MEMORY_SCOPE_AGENT);
        }
        // flag release: same wave as the h stores -> waitcnt covers them
        if (tid == 0)
            __hip_atomic_store(&flags[(t & 1) * NWG + g], t,
                               __ATOMIC_RELEASE, __HIP_MEMORY_SCOPE_AGENT);
    }
}

extern "C" void kernel_launch(void* const* d_in, const int* in_sizes, int n_in,
                              void* d_out, int out_size, void* d_ws, size_t ws_size,
                              hipStream_t stream)
{
    const int*   x     = (const int*)d_in[0];
    const float* emb   = (const float*)d_in[1];
    const float* W_ih  = (const float*)d_in[2];
    const float* W_hh  = (const float*)d_in[3];
    const float* b_ih  = (const float*)d_in[4];
    const float* b_hh  = (const float*)d_in[5];
    const float* W_out = (const float*)d_in[6];
    const float* b_out = (const float*)d_in[7];
    float* out = (float*)d_out;

    float* xg    = (float*)d_ws;                       // 4095*4096 f32
    float* hs    = xg + (size_t)NSTEP * GDIM;          // 4095*1024 f32
    float* h_buf = hs + (size_t)NSTEP * HDIM;          // 2*1024 f32
    int*   flags = (int*)(h_buf + 2 * HDIM);           // 2*256 int

    dim3 blk(256);
    dim3 g1(GDIM / 128, 32);                           // 32 x 32
    gemm_emb_kernel<<<g1, blk, 0, stream>>>(x, emb, W_ih, b_ih, b_hh, xg);

    scan_kernel<<<dim3(NWG), blk, 0, stream>>>(xg, W_hh, hs, h_buf, flags);

    dim3 g2((CDIM + 127) / 128, 32);                   // 10 x 32
    gemm_out_kernel<<<g2, blk, 0, stream>>>(hs, W_out, b_out, out);
}

// Round 3
// 8159.963 us; speedup vs baseline: 13.0184x; 6.7113x over previous
//
#include <hip/hip_runtime.h>
#include <math.h>

#define NSTEP 4095   // T-1 sequence steps
#define EDIM  512
#define HDIM  1024
#define GDIM  4096   // 4*H
#define KDIM  1024   // 2E == H == 1024 for both GEMMs
#define CDIM  1221
#define SNWG  64     // scan workgroups
#define UNITS 16     // hidden units per scan WG

__device__ __forceinline__ float sigmoidf_(float v) {
    return 1.0f / (1.0f + __expf(-v));
}
__device__ __forceinline__ float tanhf_(float v) {
    v = fminf(fmaxf(v, -15.0f), 15.0f);      // avoid inf/inf NaN
    const float e2 = __expf(2.0f * v);
    return (e2 - 1.0f) / (e2 + 1.0f);
}

// ---------------------------------------------------------------------------
// GEMM1: xg[m][n] = sum_k A[m][k]*W_ih[n][k] + b_ih[n] + b_hh[n]
//   A[m][k] = emb[x[m]][k] (k<512) ; emb[x[4095]][k-512] (k>=512)
// ---------------------------------------------------------------------------
__global__ __launch_bounds__(256) void gemm_emb_kernel(
    const int* __restrict__ x, const float* __restrict__ emb,
    const float* __restrict__ W, const float* __restrict__ b_ih,
    const float* __restrict__ b_hh, float* __restrict__ xg)
{
    __shared__ float As[8][128];
    __shared__ float Bs[8][128];
    const int tid = threadIdx.x;
    const int bm = blockIdx.y * 128, bn = blockIdx.x * 128;
    const int tx = tid & 15, ty = tid >> 4;
    const int lrow = tid >> 1;
    const int lk4  = (tid & 1) * 4;
    const int lastTok = x[NSTEP];
    const int am = bm + lrow;
    const int tokRow = (am < NSTEP) ? x[am] : 0;
    const int bnrow = bn + lrow;

    float acc[8][8];
#pragma unroll
    for (int i = 0; i < 8; ++i)
#pragma unroll
        for (int j = 0; j < 8; ++j) acc[i][j] = 0.0f;

    for (int k0 = 0; k0 < KDIM; k0 += 8) {
        const int k = k0 + lk4;
        float4 av = make_float4(0.f, 0.f, 0.f, 0.f);
        if (am < NSTEP) {
            const int tok = (k < EDIM) ? tokRow : lastTok;
            const int kk  = (k < EDIM) ? k : (k - EDIM);
            av = *(const float4*)(emb + (size_t)tok * EDIM + kk);
        }
        const float4 bv = *(const float4*)(W + (size_t)bnrow * KDIM + k);
        __syncthreads();
        As[lk4 + 0][lrow] = av.x; As[lk4 + 1][lrow] = av.y;
        As[lk4 + 2][lrow] = av.z; As[lk4 + 3][lrow] = av.w;
        Bs[lk4 + 0][lrow] = bv.x; Bs[lk4 + 1][lrow] = bv.y;
        Bs[lk4 + 2][lrow] = bv.z; Bs[lk4 + 3][lrow] = bv.w;
        __syncthreads();
#pragma unroll
        for (int kk = 0; kk < 8; ++kk) {
            const float4 a0 = *(const float4*)&As[kk][ty * 4];
            const float4 a1 = *(const float4*)&As[kk][ty * 4 + 64];
            const float4 b0 = *(const float4*)&Bs[kk][tx * 4];
            const float4 b1 = *(const float4*)&Bs[kk][tx * 4 + 64];
            const float a[8] = {a0.x, a0.y, a0.z, a0.w, a1.x, a1.y, a1.z, a1.w};
            const float b[8] = {b0.x, b0.y, b0.z, b0.w, b1.x, b1.y, b1.z, b1.w};
#pragma unroll
            for (int i = 0; i < 8; ++i)
#pragma unroll
                for (int j = 0; j < 8; ++j) acc[i][j] += a[i] * b[j];
        }
    }
#pragma unroll
    for (int i = 0; i < 8; ++i) {
        const int m = bm + ((i < 4) ? (ty * 4 + i) : (64 + ty * 4 + i - 4));
        if (m >= NSTEP) continue;
#pragma unroll
        for (int j = 0; j < 8; ++j) {
            const int n = bn + ((j < 4) ? (tx * 4 + j) : (64 + tx * 4 + j - 4));
            xg[(size_t)m * GDIM + n] = acc[i][j] + b_ih[n] + b_hh[n];
        }
    }
}

// ---------------------------------------------------------------------------
// GEMM2: out[m][n] = sum_k hs[m][k]*W_out[n][k] + b_out[n]   (N=1221)
// ---------------------------------------------------------------------------
__global__ __launch_bounds__(256) void gemm_out_kernel(
    const float* __restrict__ A, const float* __restrict__ W,
    const float* __restrict__ bias, float* __restrict__ C)
{
    __shared__ float As[8][128];
    __shared__ float Bs[8][128];
    const int tid = threadIdx.x;
    const int bm = blockIdx.y * 128, bn = blockIdx.x * 128;
    const int tx = tid & 15, ty = tid >> 4;
    const int lrow = tid >> 1;
    const int lk4  = (tid & 1) * 4;
    const int am = bm + lrow;
    const int bnrow = bn + lrow;

    float acc[8][8];
#pragma unroll
    for (int i = 0; i < 8; ++i)
#pragma unroll
        for (int j = 0; j < 8; ++j) acc[i][j] = 0.0f;

    for (int k0 = 0; k0 < KDIM; k0 += 8) {
        const int k = k0 + lk4;
        float4 av = make_float4(0.f, 0.f, 0.f, 0.f);
        if (am < NSTEP) av = *(const float4*)(A + (size_t)am * KDIM + k);
        float4 bv = make_float4(0.f, 0.f, 0.f, 0.f);
        if (bnrow < CDIM) bv = *(const float4*)(W + (size_t)bnrow * KDIM + k);
        __syncthreads();
        As[lk4 + 0][lrow] = av.x; As[lk4 + 1][lrow] = av.y;
        As[lk4 + 2][lrow] = av.z; As[lk4 + 3][lrow] = av.w;
        Bs[lk4 + 0][lrow] = bv.x; Bs[lk4 + 1][lrow] = bv.y;
        Bs[lk4 + 2][lrow] = bv.z; Bs[lk4 + 3][lrow] = bv.w;
        __syncthreads();
#pragma unroll
        for (int kk = 0; kk < 8; ++kk) {
            const float4 a0 = *(const float4*)&As[kk][ty * 4];
            const float4 a1 = *(const float4*)&As[kk][ty * 4 + 64];
            const float4 b0 = *(const float4*)&Bs[kk][tx * 4];
            const float4 b1 = *(const float4*)&Bs[kk][tx * 4 + 64];
            const float a[8] = {a0.x, a0.y, a0.z, a0.w, a1.x, a1.y, a1.z, a1.w};
            const float b[8] = {b0.x, b0.y, b0.z, b0.w, b1.x, b1.y, b1.z, b1.w};
#pragma unroll
            for (int i = 0; i < 8; ++i)
#pragma unroll
                for (int j = 0; j < 8; ++j) acc[i][j] += a[i] * b[j];
        }
    }
#pragma unroll
    for (int i = 0; i < 8; ++i) {
        const int m = bm + ((i < 4) ? (ty * 4 + i) : (64 + ty * 4 + i - 4));
        if (m >= NSTEP) continue;
#pragma unroll
        for (int j = 0; j < 8; ++j) {
            const int n = bn + ((j < 4) ? (tx * 4 + j) : (64 + tx * 4 + j - 4));
            if (n < CDIM) C[(size_t)m * CDIM + n] = acc[i][j] + bias[n];
        }
    }
}

// ---------------------------------------------------------------------------
// Persistent LSTM scan, v3. 64 WGs x 1024 threads; WG g owns hidden units
// g*16..g*16+15 (64 gate rows; weights pinned in 64 VGPRs/thread).
// Handoff: tagged 64-bit payloads hb[parity][i] = (step<<32)|bits(h_i).
// The poll IS the data load (tag+value atomic in one 8B word -> no fences,
// no flag indirection). Parity double-buffer; 2-step production slack
// guarantees no overrun. Poison tag 0xAAAAAAAA < 0 never matches a step.
// ---------------------------------------------------------------------------
__global__ __launch_bounds__(1024, 4) void scan_kernel(
    const float* __restrict__ xg, const float* __restrict__ Whh,
    float* __restrict__ hs, unsigned long long* hb)
{
    __shared__ float h_s[HDIM];
    __shared__ float gate_s[64];
    __shared__ float c_s[UNITS];
    const int g = blockIdx.x, tid = threadIdx.x;
    const int lane = tid & 63, wv = tid >> 6;    // 16 waves
    const int seg = tid & 15, lr = tid >> 4;     // lr = row 0..63
    const int q = lr >> 4, j = lr & 15;          // gate q, unit j
    const int grow = q * HDIM + g * UNITS + j;   // gate row in W_hh

    // weights: thread covers cols i*64 + seg*4 .. +3, i = 0..15
    float4 w4[16];
#pragma unroll
    for (int i = 0; i < 16; ++i)
        w4[i] = *(const float4*)(Whh + (size_t)grow * KDIM + i * 64 + seg * 4);
#pragma unroll
    for (int i = 0; i < 16; ++i)
        asm volatile("" : "+v"(w4[i].x), "+v"(w4[i].y), "+v"(w4[i].z), "+v"(w4[i].w));

    for (int i = tid; i < HDIM; i += 1024) h_s[i] = 0.0f;
    if (tid < UNITS) c_s[tid] = 0.0f;
    __syncthreads();

    for (int t = 1; t <= NSTEP; ++t) {
        // xg load overlaps the spin below (independent)
        float xgv = 0.0f;
        if (seg == 0) xgv = xg[(size_t)(t - 1) * GDIM + grow];

        if (t > 1) {
            const int par = (t - 1) & 1;
            const int el = wv * 64 + lane;       // each wave owns 64 h values
            const int want = t - 1;
            unsigned long long v;
            for (;;) {
                v = __hip_atomic_load(&hb[par * HDIM + el], __ATOMIC_RELAXED,
                                      __HIP_MEMORY_SCOPE_AGENT);
                if ((int)(v >> 32) == want) break;   // per-lane spin
            }
            h_s[el] = __uint_as_float((unsigned)v);
        }
        __syncthreads();   // (B) h_s ready

        // GEMV: this thread's 64 columns of its gate row
        float acc = 0.0f;
#pragma unroll
        for (int i = 0; i < 16; ++i) {
            const float4 h4 = *(const float4*)&h_s[i * 64 + seg * 4];
            acc += w4[i].x * h4.x + w4[i].y * h4.y +
                   w4[i].z * h4.z + w4[i].w * h4.w;
        }
        acc += __shfl_xor(acc, 1, 64);
        acc += __shfl_xor(acc, 2, 64);
        acc += __shfl_xor(acc, 4, 64);
        acc += __shfl_xor(acc, 8, 64);
        if (seg == 0) gate_s[lr] = acc + xgv;
        __syncthreads();   // (C) gate_s ready; all h_s reads complete

        if (tid < UNITS) {
            const int jj = tid;
            const float ig = sigmoidf_(gate_s[jj]);
            const float fg = sigmoidf_(gate_s[16 + jj]);
            const float gg = tanhf_(gate_s[32 + jj]);
            const float og = sigmoidf_(gate_s[48 + jj]);
            const float c  = fg * c_s[jj] + ig * gg;
            c_s[jj] = c;
            const float h = og * tanhf_(c);
            hs[(size_t)(t - 1) * HDIM + g * UNITS + jj] = h;
            const unsigned long long pv =
                ((unsigned long long)(unsigned)t << 32) | __float_as_uint(h);
            __hip_atomic_store(&hb[(t & 1) * HDIM + g * UNITS + jj], pv,
                               __ATOMIC_RELAXED, __HIP_MEMORY_SCOPE_AGENT);
        }
        // no trailing barrier: next-iter writes to h_s/gate_s are gated by
        // the spin (needs OUR tag-t store) resp. barrier (B) of t+1.
    }
}

extern "C" void kernel_launch(void* const* d_in, const int* in_sizes, int n_in,
                              void* d_out, int out_size, void* d_ws, size_t ws_size,
                              hipStream_t stream)
{
    const int*   x     = (const int*)d_in[0];
    const float* emb   = (const float*)d_in[1];
    const float* W_ih  = (const float*)d_in[2];
    const float* W_hh  = (const float*)d_in[3];
    const float* b_ih  = (const float*)d_in[4];
    const float* b_hh  = (const float*)d_in[5];
    const float* W_out = (const float*)d_in[6];
    const float* b_out = (const float*)d_in[7];
    float* out = (float*)d_out;

    float* xg = (float*)d_ws;                          // 4095*4096 f32
    float* hs = xg + (size_t)NSTEP * GDIM;             // 4095*1024 f32
    unsigned long long* hb =
        (unsigned long long*)(hs + (size_t)NSTEP * HDIM);  // 2*1024 u64 (8B aligned)

    dim3 blk(256);
    dim3 g1(GDIM / 128, 32);                           // 32 x 32
    gemm_emb_kernel<<<g1, blk, 0, stream>>>(x, emb, W_ih, b_ih, b_hh, xg);

    scan_kernel<<<dim3(SNWG), dim3(1024), 0, stream>>>(xg, W_hh, hs, hb);

    dim3 g2((CDIM + 127) / 128, 32);                   // 10 x 32
    gemm_out_kernel<<<g2, blk, 0, stream>>>(hs, W_out, b_out, out);
}